// Round 8
// baseline (362.346 us; speedup 1.0000x reference)
//
#include <hip/hip_runtime.h>
#include <hip/hip_cooperative_groups.h>
#include <stdint.h>

namespace cg = cooperative_groups;

typedef unsigned short u16;
typedef unsigned int   u32;
typedef _Float16       f16;

typedef __attribute__((ext_vector_type(2))) _Float16 half2v;
typedef __attribute__((ext_vector_type(4))) _Float16 half4v;
typedef __attribute__((ext_vector_type(8))) _Float16 half8v;
typedef __attribute__((ext_vector_type(4))) float    floatx4;

#define NXS    512
#define NYS    512
#define NHEAD  8
#define DHEAD  10
#define DMODEL 80
#define DXK    768
#define DYK    283
#define DYKP   288   // padded

__device__ inline half2v pk2(float x, float y) {
  return __builtin_bit_cast(half2v, __builtin_amdgcn_cvt_pkrtz(x, y));
}
__device__ inline half4v cvt4(float4 v) {
  return __builtin_shufflevector(pk2(v.x, v.y), pk2(v.z, v.w), 0, 1, 2, 3);
}
__device__ inline half4v h4u32(u32 a, u32 b) {
  return __builtin_shufflevector(__builtin_bit_cast(half2v, a),
                                 __builtin_bit_cast(half2v, b), 0, 1, 2, 3);
}

// =====================================================================
// fused: w_prep -> grid.sync -> proj (v1-exact bodies) -> grid.sync ->
// attn (v1-exact body). One dispatch instead of three: removes 2
// graph-node gaps and exposes attn's true duration in the profile.
// LDS is a single union buffer: attn needs 19616 f16 (39232 B) >= proj
// KV's 8960 f16 -> 4 blocks/CU (156.9 KB/CU), same residency as v1.
// Grid-stride phase loops make any grid <= 1024 correct; host sizes
// grid = min(1024, occupancy-max) for the cooperative launch.
// =====================================================================
__global__ __launch_bounds__(256) void fused(const float* __restrict__ X,
                                             const float* __restrict__ Y,
                                             const float* __restrict__ Wq,
                                             const float* __restrict__ Wk,
                                             const float* __restrict__ Wv,
                                             f16* __restrict__ Wtq,
                                             f16* __restrict__ Wtk,
                                             f16* __restrict__ Wtv,
                                             f16* __restrict__ Qw,
                                             f16* __restrict__ Kw,
                                             f16* __restrict__ Vw,
                                             float* __restrict__ O) {
  __shared__ f16 smem[19616];   // attn: Ks 11264 + Vt 8352; proj uses prefix
  cg::grid_group grid = cg::this_grid();
  const int t = threadIdx.x;
  const int wv = t >> 6, lane = t & 63, m16 = lane & 15, quad = lane >> 4;

  // ---------------- phase 0: w_prep (v1-exact values) ----------------
  for (int idx = blockIdx.x * 256 + t; idx < 80 * 768; idx += gridDim.x * 256) {
    const int c = idx / 768, k = idx - c * 768;
    Wtq[idx] = (f16)Wq[k * 80 + c];
  }
  for (int idx = blockIdx.x * 256 + t; idx < 80 * 288; idx += gridDim.x * 256) {
    const int c = idx / 288, k = idx - c * 288;
    float a = 0.f, b = 0.f;
    if (k < DYK) { a = Wk[k * 80 + c]; b = Wv[k * 80 + c]; }
    Wtk[idx] = (f16)a;
    Wtv[idx] = (f16)b;
  }
  grid.sync();

  // ---------------- phase 1: proj (v1-exact schedule) ----------------
  for (int pb = blockIdx.x; pb < 1024; pb += gridDim.x) {
    __syncthreads();   // protect LDS reuse across pb iterations / phases
    if (pb < 512) {
      // ---- Q path: 24 steps of K=32 ----
      f16* const Xs = smem;          // [64][40]
      f16* const Ws = smem + 2560;   // [80][40]
      const int row0 = pb * 64;
      const int xr_r = t >> 3, xr_k = (t & 7) << 2;
      const int wi0 = t, wi1 = t + 160;

      float4 xr0, xr1;
      uint4 wr0, wr1;
      xr0 = *(const float4*)&X[(size_t)(row0 + xr_r) * DXK + xr_k];
      xr1 = *(const float4*)&X[(size_t)(row0 + xr_r + 32) * DXK + xr_k];
      if (t < 160) {
        wr0 = *(const uint4*)&Wtq[(wi0 >> 2) * DXK + (wi0 & 3) * 8];
        wr1 = *(const uint4*)&Wtq[(wi1 >> 2) * DXK + (wi1 & 3) * 8];
      }

      floatx4 acc[5];
#pragma unroll
      for (int i = 0; i < 5; ++i) acc[i] = (floatx4){0.f, 0.f, 0.f, 0.f};

      for (int s = 0; s < 24; ++s) {
        if (s) __syncthreads();
        *(half4v*)&Xs[xr_r * 40 + xr_k] = cvt4(xr0);
        *(half4v*)&Xs[(xr_r + 32) * 40 + xr_k] = cvt4(xr1);
        if (t < 160) {
          *(uint4*)&Ws[(wi0 >> 2) * 40 + (wi0 & 3) * 8] = wr0;
          *(uint4*)&Ws[(wi1 >> 2) * 40 + (wi1 & 3) * 8] = wr1;
        }
        __syncthreads();
        if (s < 23) {
          const int k0 = (s + 1) * 32;
          xr0 = *(const float4*)&X[(size_t)(row0 + xr_r) * DXK + k0 + xr_k];
          xr1 = *(const float4*)&X[(size_t)(row0 + xr_r + 32) * DXK + k0 + xr_k];
          if (t < 160) {
            wr0 = *(const uint4*)&Wtq[(wi0 >> 2) * DXK + k0 + (wi0 & 3) * 8];
            wr1 = *(const uint4*)&Wtq[(wi1 >> 2) * DXK + k0 + (wi1 & 3) * 8];
          }
        }
        const half8v a = *(const half8v*)&Xs[(wv * 16 + m16) * 40 + quad * 8];
#pragma unroll
        for (int nt = 0; nt < 5; ++nt) {
          const half8v b = *(const half8v*)&Ws[(nt * 16 + m16) * 40 + quad * 8];
          acc[nt] = __builtin_amdgcn_mfma_f32_16x16x32_f16(a, b, acc[nt], 0, 0, 0);
        }
      }
#pragma unroll
      for (int nt = 0; nt < 5; ++nt) {
        const int col = nt * 16 + m16;
#pragma unroll
        for (int p = 0; p < 4; ++p) {
          const int grow = row0 + wv * 16 + quad * 4 + p;
          Qw[(size_t)grow * DMODEL + col] = (f16)acc[nt][p];
        }
      }
    } else {
      // ---- KV path: 9 steps of K=32 ----
      f16* const Ys  = smem;          // [64][40]
      f16* const Wks = smem + 2560;   // [80][40]
      f16* const Wvs = smem + 5760;   // [80][40]
      const int row0 = (pb - 512) * 64;
      const int wi0 = t, wi1 = t + 160;

      float yr[8];
      uint4 wk0, wk1, wv0, wv1;
#pragma unroll
      for (int i = 0; i < 8; ++i) {
        const int idx = t + 256 * i;
        const int r = idx >> 5, kk = idx & 31;
        yr[i] = Y[(size_t)(row0 + r) * DYK + kk];
      }
      if (t < 160) {
        wk0 = *(const uint4*)&Wtk[(wi0 >> 2) * DYKP + (wi0 & 3) * 8];
        wk1 = *(const uint4*)&Wtk[(wi1 >> 2) * DYKP + (wi1 & 3) * 8];
        wv0 = *(const uint4*)&Wtv[(wi0 >> 2) * DYKP + (wi0 & 3) * 8];
        wv1 = *(const uint4*)&Wtv[(wi1 >> 2) * DYKP + (wi1 & 3) * 8];
      }

      floatx4 ak[5], av[5];
#pragma unroll
      for (int i = 0; i < 5; ++i) {
        ak[i] = (floatx4){0.f, 0.f, 0.f, 0.f};
        av[i] = (floatx4){0.f, 0.f, 0.f, 0.f};
      }

      for (int s = 0; s < 9; ++s) {
        if (s) __syncthreads();
#pragma unroll
        for (int i = 0; i < 8; ++i) {
          const int idx = t + 256 * i;
          Ys[(idx >> 5) * 40 + (idx & 31)] = (f16)yr[i];
        }
        if (t < 160) {
          *(uint4*)&Wks[(wi0 >> 2) * 40 + (wi0 & 3) * 8] = wk0;
          *(uint4*)&Wks[(wi1 >> 2) * 40 + (wi1 & 3) * 8] = wk1;
          *(uint4*)&Wvs[(wi0 >> 2) * 40 + (wi0 & 3) * 8] = wv0;
          *(uint4*)&Wvs[(wi1 >> 2) * 40 + (wi1 & 3) * 8] = wv1;
        }
        __syncthreads();
        if (s < 8) {
          const int k0 = (s + 1) * 32;
#pragma unroll
          for (int i = 0; i < 8; ++i) {
            const int idx = t + 256 * i;
            const int r = idx >> 5, k = k0 + (idx & 31);
            yr[i] = (k < DYK) ? Y[(size_t)(row0 + r) * DYK + k] : 0.f;
          }
          if (t < 160) {
            wk0 = *(const uint4*)&Wtk[(wi0 >> 2) * DYKP + k0 + (wi0 & 3) * 8];
            wk1 = *(const uint4*)&Wtk[(wi1 >> 2) * DYKP + k0 + (wi1 & 3) * 8];
            wv0 = *(const uint4*)&Wtv[(wi0 >> 2) * DYKP + k0 + (wi0 & 3) * 8];
            wv1 = *(const uint4*)&Wtv[(wi1 >> 2) * DYKP + k0 + (wi1 & 3) * 8];
          }
        }
        const half8v a = *(const half8v*)&Ys[(wv * 16 + m16) * 40 + quad * 8];
#pragma unroll
        for (int nt = 0; nt < 5; ++nt) {
          const half8v bk = *(const half8v*)&Wks[(nt * 16 + m16) * 40 + quad * 8];
          ak[nt] = __builtin_amdgcn_mfma_f32_16x16x32_f16(a, bk, ak[nt], 0, 0, 0);
          const half8v bv = *(const half8v*)&Wvs[(nt * 16 + m16) * 40 + quad * 8];
          av[nt] = __builtin_amdgcn_mfma_f32_16x16x32_f16(a, bv, av[nt], 0, 0, 0);
        }
      }
#pragma unroll
      for (int nt = 0; nt < 5; ++nt) {
        const int col = nt * 16 + m16;
        const int h = col / 10, d = col - h * 10;
#pragma unroll
        for (int p = 0; p < 4; ++p) {
          const int grow = row0 + wv * 16 + quad * 4 + p;
          const int bb = grow >> 9, ny = grow & 511;
          const size_t o = (((size_t)bb * NHEAD + h) * NYS + ny) * DHEAD + d;
          Kw[o] = (f16)ak[nt][p];
          Vw[o] = (f16)av[nt][p];
        }
      }
    }
  }
  grid.sync();

  // ---------------- phase 2: attn (v1-exact body) ----------------
  for (int ab = blockIdx.x; ab < 1024; ab += gridDim.x) {
    __syncthreads();   // protect LDS reuse across ab iterations / phases
    f16* const Ks = smem;            // [512][22], d 10..15 zeroed
    f16* const Vt = smem + 11264;    // [16][522], d rows 10..15 zeroed
    const int bh = ab >> 1, hf = ab & 1;
    const int b = bh >> 3, h = bh & 7;

    const u32* Kg = (const u32*)Kw + (size_t)bh * NYS * 5;
    const u32* Vg = (const u32*)Vw + (size_t)bh * NYS * 5;
    for (int idx = t; idx < 2560; idx += 256) {
      const u32 row = (u32)idx / 5u, c = (u32)idx - row * 5u;
      const half2v kv = __builtin_bit_cast(half2v, Kg[idx]);
      Ks[row * 22 + 2 * c]     = kv[0];
      Ks[row * 22 + 2 * c + 1] = kv[1];
      const half2v vvv = __builtin_bit_cast(half2v, Vg[idx]);
      Vt[(2 * c) * 522 + row]     = vvv[0];
      Vt[(2 * c + 1) * 522 + row] = vvv[1];
    }
    for (int idx = t; idx < 3072; idx += 256) {  // Ks d-pad 10..15
      const u32 row = (u32)idx / 6u, d = 10u + ((u32)idx - row * 6u);
      Ks[row * 22 + d] = (f16)0.f;
    }
    for (int idx = t; idx < 6 * 522; idx += 256)  // Vt rows 10..15
      Vt[10 * 522 + idx] = (f16)0.f;
    __syncthreads();

    const float scale = 0.31622776601683794f;  // 1/sqrt(10)
#pragma unroll 1
    for (int i = 0; i < 4; ++i) {
      const int qt = hf * 16 + wv * 4 + i;
      const int qrow = qt * 16 + m16;
      const u32* Qg32 = (const u32*)(Qw + ((size_t)b * NXS + qrow) * DMODEL + h * DHEAD);
      float s0 = 0.f, s1 = 0.f, s2 = 0.f, s3 = 0.f;
      if (quad < 2) {
        const u32 ua = Qg32[quad * 2], ub = Qg32[quad * 2 + 1];
        const half2v ha = __builtin_bit_cast(half2v, ua);
        const half2v hb = __builtin_bit_cast(half2v, ub);
        s0 = (float)ha[0]; s1 = (float)ha[1]; s2 = (float)hb[0]; s3 = (float)hb[1];
      } else if (quad == 2) {
        const u32 ua = Qg32[4];
        const half2v ha = __builtin_bit_cast(half2v, ua);
        s0 = (float)ha[0]; s1 = (float)ha[1];
      }
      const half4v qf = __builtin_shufflevector(pk2(s0 * scale, s1 * scale),
                                                pk2(s2 * scale, s3 * scale),
                                                0, 1, 2, 3);
      floatx4 o0 = (floatx4){0.f, 0.f, 0.f, 0.f};
      floatx4 o1 = (floatx4){0.f, 0.f, 0.f, 0.f};
      float l0 = 0.f, l1 = 0.f;
      for (int kt = 0; kt < 32; kt += 2) {
#pragma unroll
        for (int u = 0; u < 2; ++u) {
          const int ktu = kt + u;
          const int kb = (ktu * 16 + m16) * 22 + quad * 4;
          const half4v kf = h4u32(*(const u32*)&Ks[kb], *(const u32*)&Ks[kb + 2]);
          const floatx4 s = __builtin_amdgcn_mfma_f32_16x16x16f16(
              kf, qf, (floatx4){0.f, 0.f, 0.f, 0.f}, 0, 0, 0);
          const float p0 = __expf(s[0]);
          const float p1 = __expf(s[1]);
          const float p2 = __expf(s[2]);
          const float p3 = __expf(s[3]);
          const half4v pf = __builtin_shufflevector(pk2(p0, p1), pk2(p2, p3),
                                                    0, 1, 2, 3);
          const int vb = m16 * 522 + ktu * 16 + quad * 4;
          const half4v vf = h4u32(*(const u32*)&Vt[vb], *(const u32*)&Vt[vb + 2]);
          if (u == 0) {
            l0 += (p0 + p1) + (p2 + p3);
            o0 = __builtin_amdgcn_mfma_f32_16x16x16f16(pf, vf, o0, 0, 0, 0);
          } else {
            l1 += (p0 + p1) + (p2 + p3);
            o1 = __builtin_amdgcn_mfma_f32_16x16x16f16(pf, vf, o1, 0, 0, 0);
          }
        }
      }
      float lp = l0 + l1;
      lp += __shfl_xor(lp, 16);
      lp += __shfl_xor(lp, 32);
#pragma unroll
      for (int p = 0; p < 4; ++p) {
        const int rq = qt * 16 + quad * 4 + p;
        const float lr = __shfl(lp, quad * 4 + p);
        if (m16 < DHEAD) {
          const float qres = (float)Qw[((size_t)b * NXS + rq) * DMODEL + h * DHEAD + m16];
          O[((size_t)b * NXS + rq) * DMODEL + h * DHEAD + m16] =
              qres + (o0[p] + o1[p]) / lr;
        }
      }
    }
  }
}

extern "C" void kernel_launch(void* const* d_in, const int* in_sizes, int n_in,
                              void* d_out, int out_size, void* d_ws, size_t ws_size,
                              hipStream_t stream) {
  const float* x  = (const float*)d_in[0];
  const float* y  = (const float*)d_in[1];
  const float* Wq = (const float*)d_in[2];
  const float* Wk = (const float*)d_in[3];
  const float* Wv = (const float*)d_in[4];
  float* out = (float*)d_out;

  char* ws = (char*)d_ws;
  f16* Wtq = (f16*)(ws);                  // 80*768*2  = 122880 B
  f16* Wtk = (f16*)(ws + 122880);         // 80*288*2  =  46080 B
  f16* Wtv = (f16*)(ws + 168960);         // 46080 B
  f16* Qw  = (f16*)(ws + 262144);         // 5242880 B
  f16* Kw  = (f16*)(ws + 5505024);
  f16* Vw  = (f16*)(ws + 10747904);

  static int gridBlocks = 0;
  if (gridBlocks == 0) {
    int perCU = 0;
    if (hipOccupancyMaxActiveBlocksPerMultiprocessor(&perCU, fused, 256, 0)
            != hipSuccess || perCU < 1)
      perCU = 1;
    hipDeviceProp_t prop;
    int dev = 0;
    hipGetDevice(&dev);
    int numCU = (hipGetDeviceProperties(&prop, dev) == hipSuccess)
                    ? prop.multiProcessorCount : 256;
    long mb = (long)perCU * numCU;
    gridBlocks = (mb < 1024) ? (int)mb : 1024;
    if (gridBlocks < 1) gridBlocks = 1;
  }

  void* args[] = {(void*)&x, (void*)&y, (void*)&Wq, (void*)&Wk, (void*)&Wv,
                  (void*)&Wtq, (void*)&Wtk, (void*)&Wtv,
                  (void*)&Qw, (void*)&Kw, (void*)&Vw, (void*)&out};
  hipLaunchCooperativeKernel((void*)fused, dim3(gridBlocks), dim3(256),
                             args, 0, stream);
}